// Round 4
// baseline (1776.564 us; speedup 1.0000x reference)
//
#include <hip/hip_runtime.h>
#include <cstdint>

// LatentFactorPooling on MI355X.
// x: (64,256,64,44) fp32, basis: (4,16,256) fp32.
// out: tokens (64,256,64) fp32 then pres (64,64) fp32.
//
// Workspace layout (floats):
//   lbn_ws     [0,16384)             normalized basis, [g][c][k]
//   invden_ws  [16384,20480)         1/max(sum_p supp,1e-6) per (s,k)
//   presraw    [20480,24576)         unnormalized presence per (s,k)
//   supp_kp    [24576,2908160)       supp, [s][k][p]  (topk kernel)
//   supp_pk    [2908160,5791744)     supp, [s][p][k]  (tokens kernel)

#define C_ 256
#define W_ 44
#define P_ 704          // 16*44 positions per stripe
#define CH_STRIDE 2816  // 64*44
#define NB_STRIDE 720896 // 256*2816
#define TOPK_ 88
#define GATE_ 0.05f
#define EPS_ 1e-6f

// ---------------- kernel A: normalize latent basis ----------------
__global__ __launch_bounds__(256) void k_norm_basis(const float* __restrict__ lb,
                                                    float* __restrict__ lbn) {
  int gk = blockIdx.x;           // g*16+k
  int t = threadIdx.x;           // channel
  float v = lb[gk * 256 + t];
  float ss = v * v;
  #pragma unroll
  for (int off = 32; off >= 1; off >>= 1) ss += __shfl_xor(ss, off);
  __shared__ float red[4];
  if ((t & 63) == 0) red[t >> 6] = ss;
  __syncthreads();
  float tot = red[0] + red[1] + red[2] + red[3];
  float scale = 1.f / fmaxf(sqrtf(tot), 1e-12f);
  int g = gk >> 4, k = gk & 15;
  lbn[((g * 256 + t) << 4) + k] = v * scale;   // [g][c][k]
}

// ---------------- kernel B: routing, wave-per-row ----------------
// 1024 threads = 16 waves; wave w = stripe row, lane l = column (l<44 active).
// Stripe pooling pads with zeros => no halo. Horizontal row-sums via shfl;
// vertical via one LDS exchange per 16-channel round (32 barriers total,
// 16 outstanding global loads/lane/round).
// NOTE: inactive lanes (l>=44) CLAMP their address to column 0 — issuing the
// unclamped load runs past the end of x at the tensor tail (round-3 crash).
__global__ __launch_bounds__(1024, 4) void k_route(const float* __restrict__ x,
                                                   const float* __restrict__ lbn,
                                                   float* __restrict__ supp_kp,
                                                   float* __restrict__ supp_pk,
                                                   float* __restrict__ invden_ws) {
  __shared__ float lbn_l[4096];     // [c][k], 16 KB
  __shared__ float rsl[16384];      // rounds: [j][1024]; epilogue: rawdot [k][704]
  __shared__ float redA[16];
  __shared__ float redB[16];
  __shared__ float redM[2];
  __shared__ float red2[16 * 16];

  const int tid = threadIdx.x;
  const int w = tid >> 6;          // row
  const int l = tid & 63;          // col
  const bool act = (l < 44);
  const int s = blockIdx.x, n = s >> 2, g = s & 3;
  const int p = w * 44 + l;

  for (int i = tid; i < 4096; i += 1024) lbn_l[i] = lbn[(g << 12) + i];

  const int lsafe = act ? l : 0;   // address clamp for inactive lanes
  const float* xb = x + (size_t)n * NB_STRIDE + (g * 16 + w) * 44 + lsafe;

  float rawdot[16];
  #pragma unroll
  for (int k = 0; k < 16; k++) rawdot[k] = 0.f;
  float sq = 0.f, pw2 = 0.f;

  __syncthreads();

  for (int rnd = 0; rnd < 16; rnd++) {
    const int c0 = rnd << 4;
    float v[16], rs[16];
    #pragma unroll
    for (int j = 0; j < 16; j++) {
      float t = xb[(size_t)(c0 + j) * CH_STRIDE];   // coalesced 176B/wave
      v[j] = act ? t : 0.f;
    }
    #pragma unroll
    for (int j = 0; j < 16; j++) {
      float lf = __shfl(v[j], (l + 63) & 63);  // lane63 holds 0 -> left edge ok
      float rt = __shfl(v[j], (l + 1) & 63);   // lane44 holds 0 -> right edge ok
      rs[j] = lf + v[j] + rt;
      rsl[(j << 10) + tid] = rs[j];
    }
    __syncthreads();
    #pragma unroll
    for (int j = 0; j < 16; j++) {
      float up = (w > 0)  ? rsl[(j << 10) + tid - 64] : 0.f;
      float dn = (w < 15) ? rsl[(j << 10) + tid + 64] : 0.f;
      float win = up + rs[j] + dn;             // 3x3 window sum = 9*pooled
      pw2 = fmaf(win, win, pw2);
      sq  = fmaf(v[j], v[j], sq);
      const float4* wp = (const float4*)&lbn_l[(c0 + j) << 4];  // uniform=broadcast
      float4 w0 = wp[0], w1 = wp[1], w2 = wp[2], w3 = wp[3];
      float a = v[j];
      rawdot[0]  = fmaf(a, w0.x, rawdot[0]);  rawdot[1]  = fmaf(a, w0.y, rawdot[1]);
      rawdot[2]  = fmaf(a, w0.z, rawdot[2]);  rawdot[3]  = fmaf(a, w0.w, rawdot[3]);
      rawdot[4]  = fmaf(a, w1.x, rawdot[4]);  rawdot[5]  = fmaf(a, w1.y, rawdot[5]);
      rawdot[6]  = fmaf(a, w1.z, rawdot[6]);  rawdot[7]  = fmaf(a, w1.w, rawdot[7]);
      rawdot[8]  = fmaf(a, w2.x, rawdot[8]);  rawdot[9]  = fmaf(a, w2.y, rawdot[9]);
      rawdot[10] = fmaf(a, w2.z, rawdot[10]); rawdot[11] = fmaf(a, w2.w, rawdot[11]);
      rawdot[12] = fmaf(a, w3.x, rawdot[12]); rawdot[13] = fmaf(a, w3.y, rawdot[13]);
      rawdot[14] = fmaf(a, w3.z, rawdot[14]); rawdot[15] = fmaf(a, w3.w, rawdot[15]);
    }
    __syncthreads();
  }

  // ---- epilogue ----
  // stripe-wide energy max
  float e_raw = sq * (1.f / 256.f);            // inactive lanes: 0
  float m = e_raw;
  #pragma unroll
  for (int off = 32; off >= 1; off >>= 1) m = fmaxf(m, __shfl_xor(m, off));
  if (l == 0) redA[w] = m;
  __syncthreads();
  if (tid == 0) {
    float mm = redA[0];
    for (int w2 = 1; w2 < 16; w2++) mm = fmaxf(mm, redA[w2]);
    redM[0] = mm;
  }
  __syncthreads();
  float M = fmaxf(redM[0], EPS_);
  float e = e_raw / M;
  float am = (e > GATE_) ? 1.f : 0.f;
  float fb = (e_raw > 0.f) ? 1.f : 0.f;
  float a = am;
  #pragma unroll
  for (int off = 32; off >= 1; off >>= 1) a += __shfl_xor(a, off);
  if (l == 0) redB[w] = a;
  __syncthreads();
  if (tid == 0) {
    float sm = 0.f;
    for (int w2 = 0; w2 < 16; w2++) sm += redB[w2];
    redM[1] = sm;
  }
  __syncthreads();
  if (redM[1] <= 0.f) am = fb;

  // rawdot -> LDS [k][704] (conflict-free: lanes consecutive p)
  if (act) {
    #pragma unroll
    for (int k = 0; k < 16; k++) rsl[k * 704 + p] = rawdot[k];
  }
  __syncthreads();

  // 3x3 pool of rawdot (linearity: pool(raw).basis == pool(raw.basis))
  float pd[16];
  #pragma unroll
  for (int k = 0; k < 16; k++) pd[k] = 0.f;
  if (act) {
    #pragma unroll
    for (int dy = -1; dy <= 1; dy++) {
      int yy = w + dy;
      if (yy < 0 || yy > 15) continue;
      #pragma unroll
      for (int dx = -1; dx <= 1; dx++) {
        int xx = l + dx;
        if (xx < 0 || xx > 43) continue;
        int pp = yy * 44 + xx;
        #pragma unroll
        for (int k = 0; k < 16; k++) pd[k] += rsl[k * 704 + pp];
      }
    }
  }

  float pnorm = sqrtf(pw2) * (1.f / 9.f);      // ||pooled||
  float invn = 1.f / fmaxf(pnorm, 1e-12f);
  float scl = invn * (8.f / 9.f);              // /9 pool, /0.125 temp
  float li[16];
  float mx = -1e30f;
  #pragma unroll
  for (int k = 0; k < 16; k++) { li[k] = pd[k] * scl; mx = fmaxf(mx, li[k]); }
  float ssum = 0.f;
  #pragma unroll
  for (int k = 0; k < 16; k++) { li[k] = __expf(li[k] - mx); ssum += li[k]; }
  float rs2 = am / ssum;
  float supp[16];
  #pragma unroll
  for (int k = 0; k < 16; k++) supp[k] = li[k] * rs2;

  if (act) {
    float* sbp = supp_kp + (size_t)s * (16 * 704);
    #pragma unroll
    for (int k = 0; k < 16; k++) sbp[k * 704 + p] = supp[k];
    float* spk = supp_pk + ((size_t)s * 704 + p) * 16;
    #pragma unroll
    for (int kq = 0; kq < 4; kq++)
      ((float4*)spk)[kq] = make_float4(supp[kq*4+0], supp[kq*4+1],
                                       supp[kq*4+2], supp[kq*4+3]);
  }

  // per-k denominators (inactive lanes contribute 0)
  #pragma unroll
  for (int k = 0; k < 16; k++) {
    float v2 = act ? supp[k] : 0.f;
    #pragma unroll
    for (int off = 32; off >= 1; off >>= 1) v2 += __shfl_xor(v2, off);
    if (l == 0) red2[w * 16 + k] = v2;
  }
  __syncthreads();
  if (tid < 16) {
    float den = 0.f;
    for (int w2 = 0; w2 < 16; w2++) den += red2[w2 * 16 + tid];
    invden_ws[s * 16 + tid] = 1.f / fmaxf(den, EPS_);
  }
}

// ---------------- kernel C: exact top-88 mean via radix select ----------------
__global__ __launch_bounds__(256) void k_topk(const float* __restrict__ supp_kp,
                                              float* __restrict__ presraw) {
  const int blk = blockIdx.x;   // s*16+k
  const int t = threadIdx.x;
  const int lane = t & 63, w = t >> 6;
  const float* v = supp_kp + (size_t)blk * 704;
  const bool h2 = (t < 192);
  uint32_t key0 = __float_as_uint(v[t]);        // supp >= 0 => bits monotone
  uint32_t key1 = __float_as_uint(v[t + 256]);
  uint32_t key2 = h2 ? __float_as_uint(v[t + 512]) : 0u;

  __shared__ uint32_t hist[256];
  __shared__ uint32_t sarr[257];
  __shared__ uint32_t wsum[4];
  __shared__ uint32_t bc0, bc1;
  uint32_t prefix = 0, remaining = TOPK_;

  for (int b = 3; b >= 0; b--) {
    hist[t] = 0u;
    __syncthreads();
    const int shift = b * 8;
    uint32_t mhi = (b == 3) ? 0u : (0xFFFFFFFFu << (shift + 8));
    if ((key0 & mhi) == (prefix & mhi)) atomicAdd(&hist[(key0 >> shift) & 255u], 1u);
    if ((key1 & mhi) == (prefix & mhi)) atomicAdd(&hist[(key1 >> shift) & 255u], 1u);
    if (h2 && ((key2 & mhi) == (prefix & mhi))) atomicAdd(&hist[(key2 >> shift) & 255u], 1u);
    __syncthreads();

    uint32_t val = hist[t];
    #pragma unroll
    for (int off = 1; off < 64; off <<= 1) {
      uint32_t o = (uint32_t)__shfl_down((int)val, off);
      if (lane + off < 64) val += o;
    }
    if (lane == 0) wsum[w] = val;
    __syncthreads();
    uint32_t add = 0;
    for (int w2 = w + 1; w2 < 4; w2++) add += wsum[w2];
    sarr[t] = val + add;
    if (t == 0) sarr[256] = 0u;
    __syncthreads();
    uint32_t s_t = sarr[t], s_n = sarr[t + 1];
    if (s_t >= remaining && s_n < remaining) {
      bc0 = prefix | ((uint32_t)t << shift);
      bc1 = remaining - s_n;
    }
    __syncthreads();
    prefix = bc0; remaining = bc1;
    __syncthreads();
  }

  float tf = __uint_as_float(prefix);
  float sgt = 0.f;
  uint32_t cgt = 0;
  if (key0 > prefix) { sgt += __uint_as_float(key0); cgt++; }
  if (key1 > prefix) { sgt += __uint_as_float(key1); cgt++; }
  if (h2 && key2 > prefix) { sgt += __uint_as_float(key2); cgt++; }
  #pragma unroll
  for (int off = 32; off >= 1; off >>= 1) {
    sgt += __shfl_xor(sgt, off);
    cgt += __shfl_xor(cgt, off);
  }
  __shared__ float rsx[4];
  __shared__ uint32_t rcx[4];
  if (lane == 0) { rsx[w] = sgt; rcx[w] = cgt; }
  __syncthreads();
  if (t == 0) {
    float stot = rsx[0] + rsx[1] + rsx[2] + rsx[3];
    uint32_t ctot = rcx[0] + rcx[1] + rcx[2] + rcx[3];
    float top = stot + (float)(TOPK_ - ctot) * tf;
    presraw[blk] = top * (1.f / (float)TOPK_);
  }
}

// ---------------- kernel 3: tokens GEMM, channel-split (2 blocks/stripe) ----------------
// block = (stripe, channel-half): 512 blocks x 512 thr => 2 blocks/CU overlap.
// Tiles of 128ch x 32pos (16 KB, xor-swizzled) + register prefetch; supp rows
// via wave-uniform scalar (readfirstlane) float4 loads.
__global__ __launch_bounds__(512, 4) void k_tokens(const float* __restrict__ x,
                                                   const float* __restrict__ supp_pk,
                                                   const float* __restrict__ invden,
                                                   float* __restrict__ out) {
  __shared__ float xl[4096];   // 128ch x 32pos; reused for quarter-reduce
  const int tid = threadIdx.x;
  const int bid = blockIdx.x;
  const int s = bid >> 1, chalf = bid & 1;
  const int n = s >> 2, g = s & 3;
  const int cl = tid & 127;               // local channel
  const int q = tid >> 7;                 // position quarter (wave-uniform)
  const int sblk = s * (704 * 16);

  const float* xs = x + (size_t)n * NB_STRIDE + (size_t)(chalf * 128) * CH_STRIDE + g * P_;

  const int li0 = tid, li1 = tid + 512;
  const int lc0 = li0 >> 3, lj0 = li0 & 7;
  const int lc1 = li1 >> 3, lj1 = li1 & 7;
  const float* gp0 = xs + (size_t)lc0 * CH_STRIDE + lj0 * 4;
  const float* gp1 = xs + (size_t)lc1 * CH_STRIDE + lj1 * 4;
  const int wo0 = lc0 * 32 + ((lj0 * 4) ^ ((lc0 & 7) * 4));
  const int wo1 = lc1 * 32 + ((lj1 * 4) ^ ((lc1 & 7) * 4));

  const int sw = (cl & 7) * 4;
  const int rbase = cl * 32;

  float acc[16];
  #pragma unroll
  for (int k = 0; k < 16; k++) acc[k] = 0.f;

  float4 r0 = *(const float4*)gp0;
  float4 r1 = *(const float4*)gp1;
  *(float4*)&xl[wo0] = r0;
  *(float4*)&xl[wo1] = r1;
  __syncthreads();

  for (int tt = 0; tt < 22; tt++) {
    const int p0 = tt * 32;
    float4 n0, n1;
    if (tt < 21) {
      n0 = *(const float4*)(gp0 + p0 + 32);
      n1 = *(const float4*)(gp1 + p0 + 32);
    }

    #pragma unroll
    for (int jj = 0; jj < 8; jj += 4) {
      const int pp0 = q * 8 + jj;
      float4 xv = *(const float4*)&xl[rbase + (pp0 ^ sw)];
      float xa[4] = {xv.x, xv.y, xv.z, xv.w};
      #pragma unroll
      for (int dj = 0; dj < 4; dj++) {
        int uofs = __builtin_amdgcn_readfirstlane(sblk + (p0 + pp0 + dj) * 16);
        const float4* sp = (const float4*)(supp_pk + uofs);
        float4 s0 = sp[0], s1 = sp[1], s2 = sp[2], s3 = sp[3];
        float a = xa[dj];
        acc[0]  += a * s0.x; acc[1]  += a * s0.y; acc[2]  += a * s0.z; acc[3]  += a * s0.w;
        acc[4]  += a * s1.x; acc[5]  += a * s1.y; acc[6]  += a * s1.z; acc[7]  += a * s1.w;
        acc[8]  += a * s2.x; acc[9]  += a * s2.y; acc[10] += a * s2.z; acc[11] += a * s2.w;
        acc[12] += a * s3.x; acc[13] += a * s3.y; acc[14] += a * s3.z; acc[15] += a * s3.w;
      }
    }

    __syncthreads();
    if (tt < 21) {
      *(float4*)&xl[wo0] = n0;
      *(float4*)&xl[wo1] = n1;
      __syncthreads();
    }
  }

  // quarter-reduce via LDS (xl reused)
  if (q >= 2) {
    float* dst = &xl[((q - 2) * 128 + cl) * 16];
    #pragma unroll
    for (int kq = 0; kq < 4; kq++)
      ((float4*)dst)[kq] = make_float4(acc[kq*4], acc[kq*4+1], acc[kq*4+2], acc[kq*4+3]);
  }
  __syncthreads();
  if (q < 2) {
    const float* src = &xl[(q * 128 + cl) * 16];
    #pragma unroll
    for (int k = 0; k < 16; k++) acc[k] += src[k];
  }
  __syncthreads();
  if (q == 1) {
    float* dst = &xl[cl * 16];
    #pragma unroll
    for (int kq = 0; kq < 4; kq++)
      ((float4*)dst)[kq] = make_float4(acc[kq*4], acc[kq*4+1], acc[kq*4+2], acc[kq*4+3]);
  }
  __syncthreads();
  if (q == 0) {
    const float* src = &xl[cl * 16];
    float* op = out + ((size_t)(n * 256 + chalf * 128 + cl) * 64) + g * 16;
    #pragma unroll
    for (int kq = 0; kq < 4; kq++) {
      int u = __builtin_amdgcn_readfirstlane(s * 16 + kq * 4);
      const float4 iv = *(const float4*)(invden + u);
      float4 o;
      o.x = (acc[kq*4+0] + src[kq*4+0]) * iv.x;
      o.y = (acc[kq*4+1] + src[kq*4+1]) * iv.y;
      o.z = (acc[kq*4+2] + src[kq*4+2]) * iv.z;
      o.w = (acc[kq*4+3] + src[kq*4+3]) * iv.w;
      ((float4*)op)[kq] = o;
    }
  }
}

// ---------------- kernel D: presence normalization ----------------
__global__ __launch_bounds__(64) void k_pres(const float* __restrict__ presraw,
                                             float* __restrict__ out) {
  const int n = blockIdx.x, t = threadIdx.x;
  float v = presraw[n * 64 + t];
  float ssum = v;
  #pragma unroll
  for (int off = 32; off >= 1; off >>= 1) ssum += __shfl_xor(ssum, off);
  out[1048576 + n * 64 + t] = v / fmaxf(ssum, EPS_);
}

extern "C" void kernel_launch(void* const* d_in, const int* in_sizes, int n_in,
                              void* d_out, int out_size, void* d_ws, size_t ws_size,
                              hipStream_t stream) {
  (void)in_sizes; (void)n_in; (void)out_size; (void)ws_size;
  const float* x  = (const float*)d_in[0];
  const float* lb = (const float*)d_in[1];
  float* out = (float*)d_out;
  float* ws = (float*)d_ws;
  float* lbn_ws     = ws;              // 16384 floats
  float* invden_ws  = ws + 16384;      // 4096
  float* presraw_ws = ws + 20480;      // 4096
  float* supp_kp_ws = ws + 24576;      // 2883584
  float* supp_pk_ws = ws + 2908160;    // 2883584

  k_norm_basis<<<64, 256, 0, stream>>>(lb, lbn_ws);
  k_route<<<256, 1024, 0, stream>>>(x, lbn_ws, supp_kp_ws, supp_pk_ws, invden_ws);
  k_topk<<<4096, 256, 0, stream>>>(supp_kp_ws, presraw_ws);
  k_tokens<<<512, 512, 0, stream>>>(x, supp_pk_ws, invden_ws, out);
  k_pres<<<64, 64, 0, stream>>>(presraw_ws, out);
}

// Round 5
// 1099.291 us; speedup vs baseline: 1.6161x; 1.6161x over previous
//
#include <hip/hip_runtime.h>
#include <cstdint>

// LatentFactorPooling on MI355X.
// x: (64,256,64,44) fp32, basis: (4,16,256) fp32.
// out: tokens (64,256,64) fp32 then pres (64,64) fp32.
//
// Workspace layout (floats):
//   lbn_ws     [0,16384)             normalized basis, [g][c][k]
//   invden_ws  [16384,20480)         1/max(sum_p supp,1e-6) per (s,k)
//   presraw    [20480,24576)         unnormalized presence per (s,k)
//   supp_kp    [24576,2908160)       supp, [s][k][p]  (topk kernel)
//   supp_pk    [2908160,5791744)     supp, [s][p][k]  (tokens kernel)

#define C_ 256
#define W_ 44
#define P_ 704          // 16*44 positions per stripe
#define CH_STRIDE 2816  // 64*44
#define NB_STRIDE 720896 // 256*2816
#define TOPK_ 88
#define GATE_ 0.05f
#define EPS_ 1e-6f

// ---------------- kernel A: normalize latent basis ----------------
__global__ __launch_bounds__(256) void k_norm_basis(const float* __restrict__ lb,
                                                    float* __restrict__ lbn) {
  int gk = blockIdx.x;           // g*16+k
  int t = threadIdx.x;           // channel
  float v = lb[gk * 256 + t];
  float ss = v * v;
  #pragma unroll
  for (int off = 32; off >= 1; off >>= 1) ss += __shfl_xor(ss, off);
  __shared__ float red[4];
  if ((t & 63) == 0) red[t >> 6] = ss;
  __syncthreads();
  float tot = red[0] + red[1] + red[2] + red[3];
  float scale = 1.f / fmaxf(sqrtf(tot), 1e-12f);
  int g = gk >> 4, k = gk & 15;
  lbn[((g * 256 + t) << 4) + k] = v * scale;   // [g][c][k]
}

// ---------------- kernel B: routing, wave-per-row (spill-free) ----------------
// 1024 threads = 16 waves; wave w = stripe row, lane l = column (l<44 active).
// 8-channel rounds; rs re-read from LDS in phase 2 (no rs[] array); next
// round's loads prefetched between the two barriers. Peak live ~60 VGPRs —
// under the 128 hard cap a 1024-thread block imposes (round-4 spill fix).
__global__ __launch_bounds__(1024) void k_route(const float* __restrict__ x,
                                                const float* __restrict__ lbn,
                                                float* __restrict__ supp_kp,
                                                float* __restrict__ supp_pk,
                                                float* __restrict__ invden_ws) {
  __shared__ float lbn_l[4096];     // [c][k], 16 KB
  __shared__ float rsl[11264];      // rounds: [j<8][1024]; epilogue: rawdot [k][704]
  __shared__ float redA[16];
  __shared__ float redB[16];
  __shared__ float redM[2];
  __shared__ float red2[16 * 16];

  const int tid = threadIdx.x;
  const int w = tid >> 6;          // row
  const int l = tid & 63;          // col
  const bool act = (l < 44);
  const int s = blockIdx.x, n = s >> 2, g = s & 3;
  const int p = w * 44 + l;

  for (int i = tid; i < 4096; i += 1024) lbn_l[i] = lbn[(g << 12) + i];

  const int lsafe = act ? l : 0;   // address clamp (round-3 OOB fix)
  const float* xb = x + (size_t)n * NB_STRIDE + (g * 16 + w) * 44 + lsafe;

  float rawdot[16];
  #pragma unroll
  for (int k = 0; k < 16; k++) rawdot[k] = 0.f;
  float sq = 0.f, pw2 = 0.f;

  float vbuf[8];
  #pragma unroll
  for (int j = 0; j < 8; j++) vbuf[j] = xb[(size_t)j * CH_STRIDE];

  __syncthreads();

  for (int rnd = 0; rnd < 32; rnd++) {
    const int c0 = rnd << 3;
    // phase 1: consume vbuf -> sq, rawdot, row-sums to LDS
    #pragma unroll
    for (int j = 0; j < 8; j++) {
      float vj = act ? vbuf[j] : 0.f;
      float lf = __shfl(vj, (l + 63) & 63);  // lane63 holds 0 -> left edge ok
      float rt = __shfl(vj, (l + 1) & 63);   // lane44 holds 0 -> right edge ok
      rsl[(j << 10) + tid] = lf + vj + rt;
      sq = fmaf(vj, vj, sq);
      const float4* wp = (const float4*)&lbn_l[(c0 + j) << 4];  // uniform
      float4 w0 = wp[0], w1 = wp[1], w2 = wp[2], w3 = wp[3];
      rawdot[0]  = fmaf(vj, w0.x, rawdot[0]);  rawdot[1]  = fmaf(vj, w0.y, rawdot[1]);
      rawdot[2]  = fmaf(vj, w0.z, rawdot[2]);  rawdot[3]  = fmaf(vj, w0.w, rawdot[3]);
      rawdot[4]  = fmaf(vj, w1.x, rawdot[4]);  rawdot[5]  = fmaf(vj, w1.y, rawdot[5]);
      rawdot[6]  = fmaf(vj, w1.z, rawdot[6]);  rawdot[7]  = fmaf(vj, w1.w, rawdot[7]);
      rawdot[8]  = fmaf(vj, w2.x, rawdot[8]);  rawdot[9]  = fmaf(vj, w2.y, rawdot[9]);
      rawdot[10] = fmaf(vj, w2.z, rawdot[10]); rawdot[11] = fmaf(vj, w2.w, rawdot[11]);
      rawdot[12] = fmaf(vj, w3.x, rawdot[12]); rawdot[13] = fmaf(vj, w3.y, rawdot[13]);
      rawdot[14] = fmaf(vj, w3.z, rawdot[14]); rawdot[15] = fmaf(vj, w3.w, rawdot[15]);
    }
    __syncthreads();

    // prefetch next round (no LDS dependency -> overlaps phase 2)
    if (rnd < 31) {
      #pragma unroll
      for (int j = 0; j < 8; j++)
        vbuf[j] = xb[(size_t)(c0 + 8 + j) * CH_STRIDE];
    }

    // phase 2: vertical 3-sum from LDS
    #pragma unroll
    for (int j = 0; j < 8; j++) {
      float up  = (w > 0)  ? rsl[(j << 10) + tid - 64] : 0.f;
      float mid = rsl[(j << 10) + tid];
      float dn  = (w < 15) ? rsl[(j << 10) + tid + 64] : 0.f;
      float win = up + mid + dn;             // 3x3 window sum = 9*pooled
      pw2 = fmaf(win, win, pw2);
    }
    __syncthreads();
  }

  // ---- epilogue ----
  // stripe-wide energy max
  float e_raw = sq * (1.f / 256.f);            // inactive lanes: 0
  float m = e_raw;
  #pragma unroll
  for (int off = 32; off >= 1; off >>= 1) m = fmaxf(m, __shfl_xor(m, off));
  if (l == 0) redA[w] = m;
  __syncthreads();
  if (tid == 0) {
    float mm = redA[0];
    for (int w2 = 1; w2 < 16; w2++) mm = fmaxf(mm, redA[w2]);
    redM[0] = mm;
  }
  __syncthreads();
  float M = fmaxf(redM[0], EPS_);
  float e = e_raw / M;
  float am = (e > GATE_) ? 1.f : 0.f;
  float fb = (e_raw > 0.f) ? 1.f : 0.f;
  float a = am;
  #pragma unroll
  for (int off = 32; off >= 1; off >>= 1) a += __shfl_xor(a, off);
  if (l == 0) redB[w] = a;
  __syncthreads();
  if (tid == 0) {
    float sm = 0.f;
    for (int w2 = 0; w2 < 16; w2++) sm += redB[w2];
    redM[1] = sm;
  }
  __syncthreads();
  if (redM[1] <= 0.f) am = fb;
  __syncthreads();   // all reads of round-phase rsl done; reuse as rawdot store

  // rawdot -> LDS [k][704] (conflict-free: lanes consecutive p)
  if (act) {
    #pragma unroll
    for (int k = 0; k < 16; k++) rsl[k * 704 + p] = rawdot[k];
  }
  __syncthreads();

  // 3x3 pool of rawdot (linearity: pool(raw).basis == pool(raw.basis))
  float pd[16];
  #pragma unroll
  for (int k = 0; k < 16; k++) pd[k] = 0.f;
  if (act) {
    #pragma unroll
    for (int dy = -1; dy <= 1; dy++) {
      int yy = w + dy;
      if (yy < 0 || yy > 15) continue;
      #pragma unroll
      for (int dx = -1; dx <= 1; dx++) {
        int xx = l + dx;
        if (xx < 0 || xx > 43) continue;
        int pp = yy * 44 + xx;
        #pragma unroll
        for (int k = 0; k < 16; k++) pd[k] += rsl[k * 704 + pp];
      }
    }
  }

  float pnorm = sqrtf(pw2) * (1.f / 9.f);      // ||pooled||
  float invn = 1.f / fmaxf(pnorm, 1e-12f);
  float scl = invn * (8.f / 9.f);              // /9 pool, /0.125 temp
  float li[16];
  float mx = -1e30f;
  #pragma unroll
  for (int k = 0; k < 16; k++) { li[k] = pd[k] * scl; mx = fmaxf(mx, li[k]); }
  float ssum = 0.f;
  #pragma unroll
  for (int k = 0; k < 16; k++) { li[k] = __expf(li[k] - mx); ssum += li[k]; }
  float rs2 = am / ssum;
  float supp[16];
  #pragma unroll
  for (int k = 0; k < 16; k++) supp[k] = li[k] * rs2;

  if (act) {
    float* sbp = supp_kp + (size_t)s * (16 * 704);
    #pragma unroll
    for (int k = 0; k < 16; k++) sbp[k * 704 + p] = supp[k];
    float* spk = supp_pk + ((size_t)s * 704 + p) * 16;
    #pragma unroll
    for (int kq = 0; kq < 4; kq++)
      ((float4*)spk)[kq] = make_float4(supp[kq*4+0], supp[kq*4+1],
                                       supp[kq*4+2], supp[kq*4+3]);
  }

  // per-k denominators (inactive lanes contribute 0)
  #pragma unroll
  for (int k = 0; k < 16; k++) {
    float v2 = act ? supp[k] : 0.f;
    #pragma unroll
    for (int off = 32; off >= 1; off >>= 1) v2 += __shfl_xor(v2, off);
    if (l == 0) red2[w * 16 + k] = v2;
  }
  __syncthreads();
  if (tid < 16) {
    float den = 0.f;
    for (int w2 = 0; w2 < 16; w2++) den += red2[w2 * 16 + tid];
    invden_ws[s * 16 + tid] = 1.f / fmaxf(den, EPS_);
  }
}

// ---------------- kernel C: exact top-88 mean via radix select ----------------
__global__ __launch_bounds__(256) void k_topk(const float* __restrict__ supp_kp,
                                              float* __restrict__ presraw) {
  const int blk = blockIdx.x;   // s*16+k
  const int t = threadIdx.x;
  const int lane = t & 63, w = t >> 6;
  const float* v = supp_kp + (size_t)blk * 704;
  const bool h2 = (t < 192);
  uint32_t key0 = __float_as_uint(v[t]);        // supp >= 0 => bits monotone
  uint32_t key1 = __float_as_uint(v[t + 256]);
  uint32_t key2 = h2 ? __float_as_uint(v[t + 512]) : 0u;

  __shared__ uint32_t hist[256];
  __shared__ uint32_t sarr[257];
  __shared__ uint32_t wsum[4];
  __shared__ uint32_t bc0, bc1;
  uint32_t prefix = 0, remaining = TOPK_;

  for (int b = 3; b >= 0; b--) {
    hist[t] = 0u;
    __syncthreads();
    const int shift = b * 8;
    uint32_t mhi = (b == 3) ? 0u : (0xFFFFFFFFu << (shift + 8));
    if ((key0 & mhi) == (prefix & mhi)) atomicAdd(&hist[(key0 >> shift) & 255u], 1u);
    if ((key1 & mhi) == (prefix & mhi)) atomicAdd(&hist[(key1 >> shift) & 255u], 1u);
    if (h2 && ((key2 & mhi) == (prefix & mhi))) atomicAdd(&hist[(key2 >> shift) & 255u], 1u);
    __syncthreads();

    uint32_t val = hist[t];
    #pragma unroll
    for (int off = 1; off < 64; off <<= 1) {
      uint32_t o = (uint32_t)__shfl_down((int)val, off);
      if (lane + off < 64) val += o;
    }
    if (lane == 0) wsum[w] = val;
    __syncthreads();
    uint32_t add = 0;
    for (int w2 = w + 1; w2 < 4; w2++) add += wsum[w2];
    sarr[t] = val + add;
    if (t == 0) sarr[256] = 0u;
    __syncthreads();
    uint32_t s_t = sarr[t], s_n = sarr[t + 1];
    if (s_t >= remaining && s_n < remaining) {
      bc0 = prefix | ((uint32_t)t << shift);
      bc1 = remaining - s_n;
    }
    __syncthreads();
    prefix = bc0; remaining = bc1;
    __syncthreads();
  }

  float tf = __uint_as_float(prefix);
  float sgt = 0.f;
  uint32_t cgt = 0;
  if (key0 > prefix) { sgt += __uint_as_float(key0); cgt++; }
  if (key1 > prefix) { sgt += __uint_as_float(key1); cgt++; }
  if (h2 && key2 > prefix) { sgt += __uint_as_float(key2); cgt++; }
  #pragma unroll
  for (int off = 32; off >= 1; off >>= 1) {
    sgt += __shfl_xor(sgt, off);
    cgt += __shfl_xor(cgt, off);
  }
  __shared__ float rsx[4];
  __shared__ uint32_t rcx[4];
  if (lane == 0) { rsx[w] = sgt; rcx[w] = cgt; }
  __syncthreads();
  if (t == 0) {
    float stot = rsx[0] + rsx[1] + rsx[2] + rsx[3];
    uint32_t ctot = rcx[0] + rcx[1] + rcx[2] + rcx[3];
    float top = stot + (float)(TOPK_ - ctot) * tf;
    presraw[blk] = top * (1.f / (float)TOPK_);
  }
}

// ---------------- kernel 3: tokens GEMM, channel-split (2 blocks/stripe) ----------------
__global__ __launch_bounds__(512, 4) void k_tokens(const float* __restrict__ x,
                                                   const float* __restrict__ supp_pk,
                                                   const float* __restrict__ invden,
                                                   float* __restrict__ out) {
  __shared__ float xl[4096];   // 128ch x 32pos; reused for quarter-reduce
  const int tid = threadIdx.x;
  const int bid = blockIdx.x;
  const int s = bid >> 1, chalf = bid & 1;
  const int n = s >> 2, g = s & 3;
  const int cl = tid & 127;               // local channel
  const int q = tid >> 7;                 // position quarter (wave-uniform)
  const int sblk = s * (704 * 16);

  const float* xs = x + (size_t)n * NB_STRIDE + (size_t)(chalf * 128) * CH_STRIDE + g * P_;

  const int li0 = tid, li1 = tid + 512;
  const int lc0 = li0 >> 3, lj0 = li0 & 7;
  const int lc1 = li1 >> 3, lj1 = li1 & 7;
  const float* gp0 = xs + (size_t)lc0 * CH_STRIDE + lj0 * 4;
  const float* gp1 = xs + (size_t)lc1 * CH_STRIDE + lj1 * 4;
  const int wo0 = lc0 * 32 + ((lj0 * 4) ^ ((lc0 & 7) * 4));
  const int wo1 = lc1 * 32 + ((lj1 * 4) ^ ((lc1 & 7) * 4));

  const int sw = (cl & 7) * 4;
  const int rbase = cl * 32;

  float acc[16];
  #pragma unroll
  for (int k = 0; k < 16; k++) acc[k] = 0.f;

  float4 r0 = *(const float4*)gp0;
  float4 r1 = *(const float4*)gp1;
  *(float4*)&xl[wo0] = r0;
  *(float4*)&xl[wo1] = r1;
  __syncthreads();

  for (int tt = 0; tt < 22; tt++) {
    const int p0 = tt * 32;
    float4 n0, n1;
    if (tt < 21) {
      n0 = *(const float4*)(gp0 + p0 + 32);
      n1 = *(const float4*)(gp1 + p0 + 32);
    }

    #pragma unroll
    for (int jj = 0; jj < 8; jj += 4) {
      const int pp0 = q * 8 + jj;
      float4 xv = *(const float4*)&xl[rbase + (pp0 ^ sw)];
      float xa[4] = {xv.x, xv.y, xv.z, xv.w};
      #pragma unroll
      for (int dj = 0; dj < 4; dj++) {
        int uofs = __builtin_amdgcn_readfirstlane(sblk + (p0 + pp0 + dj) * 16);
        const float4* sp = (const float4*)(supp_pk + uofs);
        float4 s0 = sp[0], s1 = sp[1], s2 = sp[2], s3 = sp[3];
        float a = xa[dj];
        acc[0]  += a * s0.x; acc[1]  += a * s0.y; acc[2]  += a * s0.z; acc[3]  += a * s0.w;
        acc[4]  += a * s1.x; acc[5]  += a * s1.y; acc[6]  += a * s1.z; acc[7]  += a * s1.w;
        acc[8]  += a * s2.x; acc[9]  += a * s2.y; acc[10] += a * s2.z; acc[11] += a * s2.w;
        acc[12] += a * s3.x; acc[13] += a * s3.y; acc[14] += a * s3.z; acc[15] += a * s3.w;
      }
    }

    __syncthreads();
    if (tt < 21) {
      *(float4*)&xl[wo0] = n0;
      *(float4*)&xl[wo1] = n1;
      __syncthreads();
    }
  }

  // quarter-reduce via LDS (xl reused)
  if (q >= 2) {
    float* dst = &xl[((q - 2) * 128 + cl) * 16];
    #pragma unroll
    for (int kq = 0; kq < 4; kq++)
      ((float4*)dst)[kq] = make_float4(acc[kq*4], acc[kq*4+1], acc[kq*4+2], acc[kq*4+3]);
  }
  __syncthreads();
  if (q < 2) {
    const float* src = &xl[(q * 128 + cl) * 16];
    #pragma unroll
    for (int k = 0; k < 16; k++) acc[k] += src[k];
  }
  __syncthreads();
  if (q == 1) {
    float* dst = &xl[cl * 16];
    #pragma unroll
    for (int kq = 0; kq < 4; kq++)
      ((float4*)dst)[kq] = make_float4(acc[kq*4], acc[kq*4+1], acc[kq*4+2], acc[kq*4+3]);
  }
  __syncthreads();
  if (q == 0) {
    const float* src = &xl[cl * 16];
    float* op = out + ((size_t)(n * 256 + chalf * 128 + cl) * 64) + g * 16;
    #pragma unroll
    for (int kq = 0; kq < 4; kq++) {
      int u = __builtin_amdgcn_readfirstlane(s * 16 + kq * 4);
      const float4 iv = *(const float4*)(invden + u);
      float4 o;
      o.x = (acc[kq*4+0] + src[kq*4+0]) * iv.x;
      o.y = (acc[kq*4+1] + src[kq*4+1]) * iv.y;
      o.z = (acc[kq*4+2] + src[kq*4+2]) * iv.z;
      o.w = (acc[kq*4+3] + src[kq*4+3]) * iv.w;
      ((float4*)op)[kq] = o;
    }
  }
}

// ---------------- kernel D: presence normalization ----------------
__global__ __launch_bounds__(64) void k_pres(const float* __restrict__ presraw,
                                             float* __restrict__ out) {
  const int n = blockIdx.x, t = threadIdx.x;
  float v = presraw[n * 64 + t];
  float ssum = v;
  #pragma unroll
  for (int off = 32; off >= 1; off >>= 1) ssum += __shfl_xor(ssum, off);
  out[1048576 + n * 64 + t] = v / fmaxf(ssum, EPS_);
}

extern "C" void kernel_launch(void* const* d_in, const int* in_sizes, int n_in,
                              void* d_out, int out_size, void* d_ws, size_t ws_size,
                              hipStream_t stream) {
  (void)in_sizes; (void)n_in; (void)out_size; (void)ws_size;
  const float* x  = (const float*)d_in[0];
  const float* lb = (const float*)d_in[1];
  float* out = (float*)d_out;
  float* ws = (float*)d_ws;
  float* lbn_ws     = ws;              // 16384 floats
  float* invden_ws  = ws + 16384;      // 4096
  float* presraw_ws = ws + 20480;      // 4096
  float* supp_kp_ws = ws + 24576;      // 2883584
  float* supp_pk_ws = ws + 2908160;    // 2883584

  k_norm_basis<<<64, 256, 0, stream>>>(lb, lbn_ws);
  k_route<<<256, 1024, 0, stream>>>(x, lbn_ws, supp_kp_ws, supp_pk_ws, invden_ws);
  k_topk<<<4096, 256, 0, stream>>>(supp_kp_ws, presraw_ws);
  k_tokens<<<512, 512, 0, stream>>>(x, supp_pk_ws, invden_ws, out);
  k_pres<<<64, 64, 0, stream>>>(presraw_ws, out);
}

// Round 6
// 358.872 us; speedup vs baseline: 4.9504x; 3.0632x over previous
//
#include <hip/hip_runtime.h>
#include <cstdint>

// LatentFactorPooling on MI355X.
// x: (64,256,64,44) fp32, basis: (4,16,256) fp32.
// out: tokens (64,256,64) fp32 then pres (64,64) fp32.
//
// Workspace layout (floats):
//   lbn_ws     [0,16384)             normalized basis, [g][c][k]
//   invden_ws  [16384,20480)         1/max(sum_p supp,1e-6) per (s,k)
//   presraw    [20480,24576)         unnormalized presence per (s,k)
//   supp_kp    [24576,2908160)       supp, [s][k][p]  (topk kernel)
//   supp_pk    [2908160,5791744)     supp, [s][p][k]  (tokens kernel)

#define C_ 256
#define W_ 44
#define P_ 704          // 16*44 positions per stripe
#define CH_STRIDE 2816  // 64*44
#define NB_STRIDE 720896 // 256*2816
#define TOPK_ 88
#define GATE_ 0.05f
#define EPS_ 1e-6f

// ---------------- kernel A: normalize latent basis ----------------
__global__ __launch_bounds__(256) void k_norm_basis(const float* __restrict__ lb,
                                                    float* __restrict__ lbn) {
  int gk = blockIdx.x;           // g*16+k
  int t = threadIdx.x;           // channel
  float v = lb[gk * 256 + t];
  float ss = v * v;
  #pragma unroll
  for (int off = 32; off >= 1; off >>= 1) ss += __shfl_xor(ss, off);
  __shared__ float red[4];
  if ((t & 63) == 0) red[t >> 6] = ss;
  __syncthreads();
  float tot = red[0] + red[1] + red[2] + red[3];
  float scale = 1.f / fmaxf(sqrtf(tot), 1e-12f);
  int g = gk >> 4, k = gk & 15;
  lbn[((g * 256 + t) << 4) + k] = v * scale;   // [g][c][k]
}

// ---------------- kernel B: routing, wave-per-row, barrier-free main loop --------
// 1024 threads = 16 waves; wave w = stripe row, lane l = column (l<44 active).
// Vertical pool sum via direct loads of rows w-1,w,w+1 (3x logical reads,
// L1/L2 absorb the reuse) -> NO in-loop LDS, NO barriers, ~40 live VGPRs
// (round-5 spill fix: compiler pins 1024-thr blocks at 64 VGPRs).
// Vertical-sum first, then horizontal via 2 shfls.
__global__ __launch_bounds__(1024) void k_route(const float* __restrict__ x,
                                                const float* __restrict__ lbn,
                                                float* __restrict__ supp_kp,
                                                float* __restrict__ supp_pk,
                                                float* __restrict__ invden_ws) {
  __shared__ float lbn_l[4096];     // [c][k], 16 KB
  __shared__ float rsl[11264];      // epilogue only: rawdot [k][704]
  __shared__ float redA[16];
  __shared__ float redB[16];
  __shared__ float redM[2];
  __shared__ float red2[16 * 16];

  const int tid = threadIdx.x;
  const int w = tid >> 6;          // row
  const int l = tid & 63;          // col
  const bool act = (l < 44);
  const int s = blockIdx.x, n = s >> 2, g = s & 3;
  const int p = w * 44 + l;

  for (int i = tid; i < 4096; i += 1024) lbn_l[i] = lbn[(g << 12) + i];

  const int lsafe = act ? l : 0;   // address clamp (round-3 OOB fix)
  const float* xb = x + (size_t)n * NB_STRIDE + (g * 16 + w) * 44 + lsafe;
  const float* xm = xb + ((w > 0)  ? -44 : 0);   // clamped row addresses
  const float* xp = xb + ((w < 15) ?  44 : 0);
  const bool hm = (w > 0), hp = (w < 15);

  float rawdot[16];
  #pragma unroll
  for (int k = 0; k < 16; k++) rawdot[k] = 0.f;
  float sq = 0.f, pw2 = 0.f;

  __syncthreads();   // lbn_l ready

  for (int c = 0; c < 256; c += 4) {
    float vm[4], v0[4], vp[4];
    #pragma unroll
    for (int j = 0; j < 4; j++) {
      const size_t o = (size_t)(c + j) * CH_STRIDE;
      vm[j] = xm[o]; v0[j] = xb[o]; vp[j] = xp[o];
    }
    #pragma unroll
    for (int j = 0; j < 4; j++) {
      float a  = act ? v0[j] : 0.f;
      float am_ = (act && hm) ? vm[j] : 0.f;
      float ap_ = (act && hp) ? vp[j] : 0.f;
      float vs = am_ + a + ap_;                 // vertical 3-sum first
      float lf = __shfl(vs, (l + 63) & 63);     // lane63 holds 0
      float rt = __shfl(vs, (l + 1) & 63);      // lane44 holds 0
      float win = lf + vs + rt;                 // 3x3 window sum = 9*pooled
      pw2 = fmaf(win, win, pw2);
      sq  = fmaf(a, a, sq);
      const float4* wp = (const float4*)&lbn_l[(c + j) << 4];  // uniform bcast
      float4 w0 = wp[0], w1 = wp[1], w2 = wp[2], w3 = wp[3];
      rawdot[0]  = fmaf(a, w0.x, rawdot[0]);  rawdot[1]  = fmaf(a, w0.y, rawdot[1]);
      rawdot[2]  = fmaf(a, w0.z, rawdot[2]);  rawdot[3]  = fmaf(a, w0.w, rawdot[3]);
      rawdot[4]  = fmaf(a, w1.x, rawdot[4]);  rawdot[5]  = fmaf(a, w1.y, rawdot[5]);
      rawdot[6]  = fmaf(a, w1.z, rawdot[6]);  rawdot[7]  = fmaf(a, w1.w, rawdot[7]);
      rawdot[8]  = fmaf(a, w2.x, rawdot[8]);  rawdot[9]  = fmaf(a, w2.y, rawdot[9]);
      rawdot[10] = fmaf(a, w2.z, rawdot[10]); rawdot[11] = fmaf(a, w2.w, rawdot[11]);
      rawdot[12] = fmaf(a, w3.x, rawdot[12]); rawdot[13] = fmaf(a, w3.y, rawdot[13]);
      rawdot[14] = fmaf(a, w3.z, rawdot[14]); rawdot[15] = fmaf(a, w3.w, rawdot[15]);
    }
  }

  // ---- epilogue ----
  // stripe-wide energy max
  float e_raw = sq * (1.f / 256.f);            // inactive lanes: 0
  float m = e_raw;
  #pragma unroll
  for (int off = 32; off >= 1; off >>= 1) m = fmaxf(m, __shfl_xor(m, off));
  if (l == 0) redA[w] = m;
  __syncthreads();
  if (tid == 0) {
    float mm = redA[0];
    for (int w2 = 1; w2 < 16; w2++) mm = fmaxf(mm, redA[w2]);
    redM[0] = mm;
  }
  __syncthreads();
  float M = fmaxf(redM[0], EPS_);
  float e = e_raw / M;
  float am = (e > GATE_) ? 1.f : 0.f;
  float fb = (e_raw > 0.f) ? 1.f : 0.f;
  float a = am;
  #pragma unroll
  for (int off = 32; off >= 1; off >>= 1) a += __shfl_xor(a, off);
  if (l == 0) redB[w] = a;
  __syncthreads();
  if (tid == 0) {
    float sm = 0.f;
    for (int w2 = 0; w2 < 16; w2++) sm += redB[w2];
    redM[1] = sm;
  }
  __syncthreads();
  if (redM[1] <= 0.f) am = fb;

  // rawdot -> LDS [k][704] (conflict-free: lanes consecutive p)
  if (act) {
    #pragma unroll
    for (int k = 0; k < 16; k++) rsl[k * 704 + p] = rawdot[k];
  }
  __syncthreads();

  // 3x3 pool of rawdot (linearity: pool(raw).basis == pool(raw.basis))
  float pd[16];
  #pragma unroll
  for (int k = 0; k < 16; k++) pd[k] = 0.f;
  if (act) {
    #pragma unroll
    for (int dy = -1; dy <= 1; dy++) {
      int yy = w + dy;
      if (yy < 0 || yy > 15) continue;
      #pragma unroll
      for (int dx = -1; dx <= 1; dx++) {
        int xx = l + dx;
        if (xx < 0 || xx > 43) continue;
        int pp = yy * 44 + xx;
        #pragma unroll
        for (int k = 0; k < 16; k++) pd[k] += rsl[k * 704 + pp];
      }
    }
  }

  float pnorm = sqrtf(pw2) * (1.f / 9.f);      // ||pooled||
  float invn = 1.f / fmaxf(pnorm, 1e-12f);
  float scl = invn * (8.f / 9.f);              // /9 pool, /0.125 temp
  float li[16];
  float mx = -1e30f;
  #pragma unroll
  for (int k = 0; k < 16; k++) { li[k] = pd[k] * scl; mx = fmaxf(mx, li[k]); }
  float ssum = 0.f;
  #pragma unroll
  for (int k = 0; k < 16; k++) { li[k] = __expf(li[k] - mx); ssum += li[k]; }
  float rs2 = am / ssum;
  float supp[16];
  #pragma unroll
  for (int k = 0; k < 16; k++) supp[k] = li[k] * rs2;

  if (act) {
    float* sbp = supp_kp + (size_t)s * (16 * 704);
    #pragma unroll
    for (int k = 0; k < 16; k++) sbp[k * 704 + p] = supp[k];
    float* spk = supp_pk + ((size_t)s * 704 + p) * 16;
    #pragma unroll
    for (int kq = 0; kq < 4; kq++)
      ((float4*)spk)[kq] = make_float4(supp[kq*4+0], supp[kq*4+1],
                                       supp[kq*4+2], supp[kq*4+3]);
  }

  // per-k denominators (inactive lanes contribute 0)
  #pragma unroll
  for (int k = 0; k < 16; k++) {
    float v2 = act ? supp[k] : 0.f;
    #pragma unroll
    for (int off = 32; off >= 1; off >>= 1) v2 += __shfl_xor(v2, off);
    if (l == 0) red2[w * 16 + k] = v2;
  }
  __syncthreads();
  if (tid < 16) {
    float den = 0.f;
    for (int w2 = 0; w2 < 16; w2++) den += red2[w2 * 16 + tid];
    invden_ws[s * 16 + tid] = 1.f / fmaxf(den, EPS_);
  }
}

// ---------------- kernel C: exact top-88 mean via radix select ----------------
__global__ __launch_bounds__(256) void k_topk(const float* __restrict__ supp_kp,
                                              float* __restrict__ presraw) {
  const int blk = blockIdx.x;   // s*16+k
  const int t = threadIdx.x;
  const int lane = t & 63, w = t >> 6;
  const float* v = supp_kp + (size_t)blk * 704;
  const bool h2 = (t < 192);
  uint32_t key0 = __float_as_uint(v[t]);        // supp >= 0 => bits monotone
  uint32_t key1 = __float_as_uint(v[t + 256]);
  uint32_t key2 = h2 ? __float_as_uint(v[t + 512]) : 0u;

  __shared__ uint32_t hist[256];
  __shared__ uint32_t sarr[257];
  __shared__ uint32_t wsum[4];
  __shared__ uint32_t bc0, bc1;
  uint32_t prefix = 0, remaining = TOPK_;

  for (int b = 3; b >= 0; b--) {
    hist[t] = 0u;
    __syncthreads();
    const int shift = b * 8;
    uint32_t mhi = (b == 3) ? 0u : (0xFFFFFFFFu << (shift + 8));
    if ((key0 & mhi) == (prefix & mhi)) atomicAdd(&hist[(key0 >> shift) & 255u], 1u);
    if ((key1 & mhi) == (prefix & mhi)) atomicAdd(&hist[(key1 >> shift) & 255u], 1u);
    if (h2 && ((key2 & mhi) == (prefix & mhi))) atomicAdd(&hist[(key2 >> shift) & 255u], 1u);
    __syncthreads();

    uint32_t val = hist[t];
    #pragma unroll
    for (int off = 1; off < 64; off <<= 1) {
      uint32_t o = (uint32_t)__shfl_down((int)val, off);
      if (lane + off < 64) val += o;
    }
    if (lane == 0) wsum[w] = val;
    __syncthreads();
    uint32_t add = 0;
    for (int w2 = w + 1; w2 < 4; w2++) add += wsum[w2];
    sarr[t] = val + add;
    if (t == 0) sarr[256] = 0u;
    __syncthreads();
    uint32_t s_t = sarr[t], s_n = sarr[t + 1];
    if (s_t >= remaining && s_n < remaining) {
      bc0 = prefix | ((uint32_t)t << shift);
      bc1 = remaining - s_n;
    }
    __syncthreads();
    prefix = bc0; remaining = bc1;
    __syncthreads();
  }

  float tf = __uint_as_float(prefix);
  float sgt = 0.f;
  uint32_t cgt = 0;
  if (key0 > prefix) { sgt += __uint_as_float(key0); cgt++; }
  if (key1 > prefix) { sgt += __uint_as_float(key1); cgt++; }
  if (h2 && key2 > prefix) { sgt += __uint_as_float(key2); cgt++; }
  #pragma unroll
  for (int off = 32; off >= 1; off >>= 1) {
    sgt += __shfl_xor(sgt, off);
    cgt += __shfl_xor(cgt, off);
  }
  __shared__ float rsx[4];
  __shared__ uint32_t rcx[4];
  if (lane == 0) { rsx[w] = sgt; rcx[w] = cgt; }
  __syncthreads();
  if (t == 0) {
    float stot = rsx[0] + rsx[1] + rsx[2] + rsx[3];
    uint32_t ctot = rcx[0] + rcx[1] + rcx[2] + rcx[3];
    float top = stot + (float)(TOPK_ - ctot) * tf;
    presraw[blk] = top * (1.f / (float)TOPK_);
  }
}

// ---------------- kernel 3: tokens GEMM, channel-split (2 blocks/stripe) ----------------
__global__ __launch_bounds__(512, 4) void k_tokens(const float* __restrict__ x,
                                                   const float* __restrict__ supp_pk,
                                                   const float* __restrict__ invden,
                                                   float* __restrict__ out) {
  __shared__ float xl[4096];   // 128ch x 32pos; reused for quarter-reduce
  const int tid = threadIdx.x;
  const int bid = blockIdx.x;
  const int s = bid >> 1, chalf = bid & 1;
  const int n = s >> 2, g = s & 3;
  const int cl = tid & 127;               // local channel
  const int q = tid >> 7;                 // position quarter (wave-uniform)
  const int sblk = s * (704 * 16);

  const float* xs = x + (size_t)n * NB_STRIDE + (size_t)(chalf * 128) * CH_STRIDE + g * P_;

  const int li0 = tid, li1 = tid + 512;
  const int lc0 = li0 >> 3, lj0 = li0 & 7;
  const int lc1 = li1 >> 3, lj1 = li1 & 7;
  const float* gp0 = xs + (size_t)lc0 * CH_STRIDE + lj0 * 4;
  const float* gp1 = xs + (size_t)lc1 * CH_STRIDE + lj1 * 4;
  const int wo0 = lc0 * 32 + ((lj0 * 4) ^ ((lc0 & 7) * 4));
  const int wo1 = lc1 * 32 + ((lj1 * 4) ^ ((lc1 & 7) * 4));

  const int sw = (cl & 7) * 4;
  const int rbase = cl * 32;

  float acc[16];
  #pragma unroll
  for (int k = 0; k < 16; k++) acc[k] = 0.f;

  float4 r0 = *(const float4*)gp0;
  float4 r1 = *(const float4*)gp1;
  *(float4*)&xl[wo0] = r0;
  *(float4*)&xl[wo1] = r1;
  __syncthreads();

  for (int tt = 0; tt < 22; tt++) {
    const int p0 = tt * 32;
    float4 n0, n1;
    if (tt < 21) {
      n0 = *(const float4*)(gp0 + p0 + 32);
      n1 = *(const float4*)(gp1 + p0 + 32);
    }

    #pragma unroll
    for (int jj = 0; jj < 8; jj += 4) {
      const int pp0 = q * 8 + jj;
      float4 xv = *(const float4*)&xl[rbase + (pp0 ^ sw)];
      float xa[4] = {xv.x, xv.y, xv.z, xv.w};
      #pragma unroll
      for (int dj = 0; dj < 4; dj++) {
        int uofs = __builtin_amdgcn_readfirstlane(sblk + (p0 + pp0 + dj) * 16);
        const float4* sp = (const float4*)(supp_pk + uofs);
        float4 s0 = sp[0], s1 = sp[1], s2 = sp[2], s3 = sp[3];
        float a = xa[dj];
        acc[0]  += a * s0.x; acc[1]  += a * s0.y; acc[2]  += a * s0.z; acc[3]  += a * s0.w;
        acc[4]  += a * s1.x; acc[5]  += a * s1.y; acc[6]  += a * s1.z; acc[7]  += a * s1.w;
        acc[8]  += a * s2.x; acc[9]  += a * s2.y; acc[10] += a * s2.z; acc[11] += a * s2.w;
        acc[12] += a * s3.x; acc[13] += a * s3.y; acc[14] += a * s3.z; acc[15] += a * s3.w;
      }
    }

    __syncthreads();
    if (tt < 21) {
      *(float4*)&xl[wo0] = n0;
      *(float4*)&xl[wo1] = n1;
      __syncthreads();
    }
  }

  // quarter-reduce via LDS (xl reused)
  if (q >= 2) {
    float* dst = &xl[((q - 2) * 128 + cl) * 16];
    #pragma unroll
    for (int kq = 0; kq < 4; kq++)
      ((float4*)dst)[kq] = make_float4(acc[kq*4], acc[kq*4+1], acc[kq*4+2], acc[kq*4+3]);
  }
  __syncthreads();
  if (q < 2) {
    const float* src = &xl[(q * 128 + cl) * 16];
    #pragma unroll
    for (int k = 0; k < 16; k++) acc[k] += src[k];
  }
  __syncthreads();
  if (q == 1) {
    float* dst = &xl[cl * 16];
    #pragma unroll
    for (int kq = 0; kq < 4; kq++)
      ((float4*)dst)[kq] = make_float4(acc[kq*4], acc[kq*4+1], acc[kq*4+2], acc[kq*4+3]);
  }
  __syncthreads();
  if (q == 0) {
    const float* src = &xl[cl * 16];
    float* op = out + ((size_t)(n * 256 + chalf * 128 + cl) * 64) + g * 16;
    #pragma unroll
    for (int kq = 0; kq < 4; kq++) {
      int u = __builtin_amdgcn_readfirstlane(s * 16 + kq * 4);
      const float4 iv = *(const float4*)(invden + u);
      float4 o;
      o.x = (acc[kq*4+0] + src[kq*4+0]) * iv.x;
      o.y = (acc[kq*4+1] + src[kq*4+1]) * iv.y;
      o.z = (acc[kq*4+2] + src[kq*4+2]) * iv.z;
      o.w = (acc[kq*4+3] + src[kq*4+3]) * iv.w;
      ((float4*)op)[kq] = o;
    }
  }
}

// ---------------- kernel D: presence normalization ----------------
__global__ __launch_bounds__(64) void k_pres(const float* __restrict__ presraw,
                                             float* __restrict__ out) {
  const int n = blockIdx.x, t = threadIdx.x;
  float v = presraw[n * 64 + t];
  float ssum = v;
  #pragma unroll
  for (int off = 32; off >= 1; off >>= 1) ssum += __shfl_xor(ssum, off);
  out[1048576 + n * 64 + t] = v / fmaxf(ssum, EPS_);
}

extern "C" void kernel_launch(void* const* d_in, const int* in_sizes, int n_in,
                              void* d_out, int out_size, void* d_ws, size_t ws_size,
                              hipStream_t stream) {
  (void)in_sizes; (void)n_in; (void)out_size; (void)ws_size;
  const float* x  = (const float*)d_in[0];
  const float* lb = (const float*)d_in[1];
  float* out = (float*)d_out;
  float* ws = (float*)d_ws;
  float* lbn_ws     = ws;              // 16384 floats
  float* invden_ws  = ws + 16384;      // 4096
  float* presraw_ws = ws + 20480;      // 4096
  float* supp_kp_ws = ws + 24576;      // 2883584
  float* supp_pk_ws = ws + 2908160;    // 2883584

  k_norm_basis<<<64, 256, 0, stream>>>(lb, lbn_ws);
  k_route<<<256, 1024, 0, stream>>>(x, lbn_ws, supp_kp_ws, supp_pk_ws, invden_ws);
  k_topk<<<4096, 256, 0, stream>>>(supp_kp_ws, presraw_ws);
  k_tokens<<<512, 512, 0, stream>>>(x, supp_pk_ws, invden_ws, out);
  k_pres<<<64, 64, 0, stream>>>(presraw_ws, out);
}